// Round 1
// baseline (524.704 us; speedup 1.0000x reference)
//
#include <hip/hip_runtime.h>
#include <cstddef>
#include <cstdint>

#define NEGV -1e30f

constexpr int B_    = 32;
constexpr int TXT   = 256;
constexpr int MEL   = 2048;
constexpr int NMEL  = 80;

// ---------------------------------------------------------------------------
// Kernel P: per (b,j): iv[c]=exp(-logvar), m2[c]=2*mu*iv, s = sum(mu^2*iv + logvar)
// Writes IV/M2 transposed to [b][c][j] for coalesced LDS staging in kernel 1.
// ---------------------------------------------------------------------------
__global__ __launch_bounds__(256) void precompute_kernel(
    const float* __restrict__ mu_logvar,
    float* __restrict__ IV, float* __restrict__ M2, float* __restrict__ S)
{
    const int b = blockIdx.x;
    const int j = threadIdx.x;
    const float* row = mu_logvar + (size_t)(b * TXT + j) * (2 * NMEL);
    float s = 0.f;
    for (int c = 0; c < NMEL; ++c) {
        float mu = row[c];
        float lv = row[NMEL + c];
        float iv = expf(-lv);
        IV[(b * NMEL + c) * TXT + j] = iv;
        M2[(b * NMEL + c) * TXT + j] = 2.0f * mu * iv;
        s += mu * mu * iv + lv;
    }
    S[b * TXT + j] = s;
}

// ---------------------------------------------------------------------------
// Kernel 1: log_prob. Tile 64 j x 128 t per block (256 threads).
// Epilogue: result tile staged in LDS (union with sIV/sM2 -> no extra LDS),
// then BOTH writes are dense float4 stores:
//   out1[b][j][t]  : lanes contiguous in t (512B/instr)
//   lpT [b][t][j]  : lanes contiguous in j (256B-dense rows)
// This removes the 1KB-strided 4B-scattered lpT stores (16x transaction
// amplification) of the previous version.
// ---------------------------------------------------------------------------
__global__ __launch_bounds__(256) void logprob_kernel(
    const float* __restrict__ mel,
    const float* __restrict__ IV, const float* __restrict__ M2,
    const float* __restrict__ S,
    float* __restrict__ out1,          // d_out + 1 (log_prob region)
    float* __restrict__ lpT,           // ws transposed copy [b][t][j]
    int write_lpT)
{
    const int tt0 = blockIdx.x * 128;
    const int j0  = blockIdx.y * 64;
    const int b   = blockIdx.z;
    const int tx  = threadIdx.x & 15;
    const int ty  = threadIdx.x >> 4;

    // 40,960 B staging buffer unioned with 33,792 B transpose tile.
    // Pad 132 (mult of 4) keeps float4 rows 16B-aligned; bank spread is
    // 4jl+t mod 32 -> worst ~8-way on the epilogue reads, negligible
    // vs the main loop (~15k cy/block).
    __shared__ union SM {
        struct { float IV[NMEL][64]; float M2[NMEL][64]; } stage;
        float V[64][132];
    } sm;

    for (int idx = threadIdx.x; idx < NMEL * 64; idx += 256) {
        int c  = idx >> 6;
        int jj = idx & 63;
        sm.stage.IV[c][jj] = IV[(b * NMEL + c) * TXT + j0 + jj];
        sm.stage.M2[c][jj] = M2[(b * NMEL + c) * TXT + j0 + jj];
    }
    __syncthreads();

    float acc[4][8];
#pragma unroll
    for (int a = 0; a < 4; ++a)
#pragma unroll
        for (int d = 0; d < 8; ++d) acc[a][d] = 0.f;

    const float* melb = mel + (size_t)b * NMEL * MEL + tt0 + tx;

#pragma unroll 2
    for (int c = 0; c < NMEL; ++c) {
        float x[8];
#pragma unroll
        for (int d = 0; d < 8; ++d) x[d] = melb[(size_t)c * MEL + 16 * d];
        float4 iv = *(const float4*)&sm.stage.IV[c][ty * 4];
        float4 m2 = *(const float4*)&sm.stage.M2[c][ty * 4];
        float ivr[4] = {iv.x, iv.y, iv.z, iv.w};
        float m2r[4] = {m2.x, m2.y, m2.z, m2.w};
#pragma unroll
        for (int a = 0; a < 4; ++a) {
#pragma unroll
            for (int d = 0; d < 8; ++d) {
                float tmp = fmaf(ivr[a], x[d], -m2r[a]);
                acc[a][d] = fmaf(tmp, x[d], acc[a][d]);
            }
        }
    }

    const float c0 = -0.5f / (float)NMEL;
    float4 sj = *(const float4*)&S[b * TXT + j0 + ty * 4];
    float sjr[4] = {sj.x, sj.y, sj.z, sj.w};

    // ---- epilogue: dump tile to LDS, then dense float4 stores both ways ----
    __syncthreads();   // everyone done reading stage.IV/stage.M2
#pragma unroll
    for (int a = 0; a < 4; ++a) {
        const int jl = ty * 4 + a;
#pragma unroll
        for (int d = 0; d < 8; ++d) {
            sm.V[jl][tx + 16 * d] = c0 * (acc[a][d] + sjr[a]);
        }
    }
    __syncthreads();

    const int tid = threadIdx.x;

    // out1[b][j][t]: thread -> (jl = (tid>>5)+8k, t4 = (tid&31)*4)
    // per wave-instr: 2 j-rows x 512B contiguous in t.
    {
        const int t4 = (tid & 31) * 4;
        const int jb = tid >> 5;
#pragma unroll
        for (int k = 0; k < 8; ++k) {
            const int jl = jb + 8 * k;
            float4 v = *(const float4*)&sm.V[jl][t4];
            *(float4*)&out1[(size_t)(b * TXT + j0 + jl) * MEL + tt0 + t4] = v;
        }
    }

    // lpT[b][t][j]: thread -> (j4 = (tid&15)*4, tl = (tid>>4)+16k)
    // per wave-instr: 4 t-rows x 256B contiguous in j.
    if (write_lpT) {
        const int j4 = (tid & 15) * 4;
        const int tb = tid >> 4;
#pragma unroll
        for (int k = 0; k < 8; ++k) {
            const int tl = tb + 16 * k;
            float4 v;
            v.x = sm.V[j4 + 0][tl];
            v.y = sm.V[j4 + 1][tl];
            v.z = sm.V[j4 + 2][tl];
            v.w = sm.V[j4 + 3][tl];
            *(float4*)&lpT[((size_t)b * MEL + tt0 + tl) * TXT + j0 + j4] = v;
        }
    }
}

// ---------------------------------------------------------------------------
// DP kernel v3 (UNCHANGED this round): one wave per batch; lane l owns
// j = 4l..4l+3. 16-deep named-register prefetch ring, DPP wave_ror:1 for the
// lane-boundary j-1 dependency.
// ---------------------------------------------------------------------------
__device__ __forceinline__ float wave_ror1(float x) {
    int xi = __float_as_int(x);
    int r  = __builtin_amdgcn_update_dpp(xi, xi, 0x13C /*wave_ror:1*/, 0xF, 0xF, false);
    return __int_as_float(r);
}

__device__ __forceinline__ float lse2(float a, float b) {
    float mx = fmaxf(a, b);
    float d  = -fabsf(a - b);
    return mx + __logf(1.0f + __expf(d));
}

__global__ __launch_bounds__(64) void dp_kernel(
    const float* __restrict__ lpT,
    const int* __restrict__ tlen, const int* __restrict__ mlen,
    float* __restrict__ alpha)
{
    const int b = blockIdx.x;
    const int l = threadIdx.x;          // 0..63

    const int tl   = tlen[b];
    const int ml   = mlen[b];
    const int tmax = ml - 1;            // last t index (>= 1023 for this shape)
    const int jt   = tl - 1;            // last j index
    const float inv_ml = 1.0f / (float)ml;

    // row stride in float4 units = TXT/4 = 64
    const float4* base = (const float4*)(lpT + (size_t)b * MEL * TXT) + l;
    const bool z = (l == 0);

    // t = 0 init
    float4 ld0 = base[0];
    float c0 = z ? ld0.x : NEGV;
    float c1 = NEGV, c2 = NEGV, c3 = NEGV;

    if (tmax <= 0) {
        const int lf = jt >> 2, ef = jt & 3;
        float v = (ef == 0) ? c0 : NEGV;
        if (l == lf) alpha[b] = v * inv_ml;
        return;
    }

    // named 16-deep ring: slot i holds row t+i (initially rows 1..16)
    float4 r0  = base[(size_t) 1 * 64];
    float4 r1  = base[(size_t) 2 * 64];
    float4 r2  = base[(size_t) 3 * 64];
    float4 r3  = base[(size_t) 4 * 64];
    float4 r4  = base[(size_t) 5 * 64];
    float4 r5  = base[(size_t) 6 * 64];
    float4 r6  = base[(size_t) 7 * 64];
    float4 r7  = base[(size_t) 8 * 64];
    float4 r8  = base[(size_t) 9 * 64];
    float4 r9  = base[(size_t)10 * 64];
    float4 r10 = base[(size_t)11 * 64];
    float4 r11 = base[(size_t)12 * 64];
    float4 r12 = base[(size_t)13 * 64];
    float4 r13 = base[(size_t)14 * 64];
    float4 r14 = base[(size_t)15 * 64];
    float4 r15 = base[(size_t)16 * 64];

#define DP_CORE(LP)                                            \
    {                                                          \
        float sw = wave_ror1(c3);                              \
        sw = z ? NEGV : sw;                                    \
        float n0 = lse2(c0, sw) + (LP).x;                      \
        float n1 = lse2(c1, c0) + (LP).y;                      \
        float n2 = lse2(c2, c1) + (LP).z;                      \
        float n3 = lse2(c3, c2) + (LP).w;                      \
        c0 = n0; c1 = n1; c2 = n2; c3 = n3;                    \
    }

// consume slot RS (row t+S), refill with row t+S+16 (lpT padded -> in bounds)
#define DP_STEP(RS, S)                                         \
    {                                                          \
        float4 lp = RS;                                        \
        RS = base[(size_t)(t + (S) + 16) * 64];                \
        DP_CORE(lp);                                           \
    }

    int t = 1;
    for (; t + 15 <= tmax; t += 16) {
        DP_STEP(r0,  0)  DP_STEP(r1,  1)  DP_STEP(r2,  2)  DP_STEP(r3,  3)
        DP_STEP(r4,  4)  DP_STEP(r5,  5)  DP_STEP(r6,  6)  DP_STEP(r7,  7)
        DP_STEP(r8,  8)  DP_STEP(r9,  9)  DP_STEP(r10, 10) DP_STEP(r11, 11)
        DP_STEP(r12, 12) DP_STEP(r13, 13) DP_STEP(r14, 14) DP_STEP(r15, 15)
    }

    // tail: <=15 remaining steps, uniform conditions, slots already hold rows t..t+15
#define DP_TAIL(RS, S)                                         \
    if (t + (S) <= tmax) { DP_CORE(RS); }

    DP_TAIL(r0,  0)  DP_TAIL(r1,  1)  DP_TAIL(r2,  2)  DP_TAIL(r3,  3)
    DP_TAIL(r4,  4)  DP_TAIL(r5,  5)  DP_TAIL(r6,  6)  DP_TAIL(r7,  7)
    DP_TAIL(r8,  8)  DP_TAIL(r9,  9)  DP_TAIL(r10, 10) DP_TAIL(r11, 11)
    DP_TAIL(r12, 12) DP_TAIL(r13, 13) DP_TAIL(r14, 14)

#undef DP_TAIL
#undef DP_STEP
#undef DP_CORE

    const int lf = jt >> 2;
    const int ef = jt & 3;
    float v = (ef == 0) ? c0 : (ef == 1) ? c1 : (ef == 2) ? c2 : c3;
    if (l == lf) alpha[b] = v * inv_ml;
}

// ---------------------------------------------------------------------------
// DP fallback (un-transposed reads) if ws too small — correctness safety net.
// ---------------------------------------------------------------------------
__global__ __launch_bounds__(256) void dp_kernel_fallback(
    const float* __restrict__ lp,
    const int* __restrict__ tlen, const int* __restrict__ mlen,
    float* __restrict__ alpha)
{
    const int b    = blockIdx.x;
    const int j    = threadIdx.x;
    const int lane = j & 63;
    const int w    = j >> 6;

    const int tl   = tlen[b];
    const int ml   = mlen[b];
    const int tmax = ml - 1;
    const int jt   = tl - 1;
    const float inv_ml = 1.0f / (float)ml;

    __shared__ float bnd[2][4];
    if (threadIdx.x < 8) bnd[threadIdx.x >> 2][threadIdx.x & 3] = NEGV;
    __syncthreads();

    float cur = (j == 0) ? lp[(size_t)(b * TXT) * MEL] : NEGV;
    if (tmax == 0) {
        if (j == jt) alpha[b] = cur * inv_ml;
        return;
    }
    int p = 0;
    for (int t = 1; t <= tmax; ++t) {
        float lpc = lp[((size_t)(b * TXT + j)) * MEL + t];
        float sh = __shfl_up(cur, 1);
        if (lane == 0) sh = (w > 0) ? bnd[p][w - 1] : NEGV;
        float mx = fmaxf(cur, sh);
        float dd = fminf(cur, sh) - mx;
        float nv = mx + __logf(1.0f + __expf(dd)) + lpc;
        if (lane == 63) bnd[p ^ 1][w] = nv;
        if (t == tmax && j == jt) alpha[b] = nv * inv_ml;
        cur = nv;
        __syncthreads();
        p ^= 1;
    }
}

// ---------------------------------------------------------------------------
// Reduce: loss = -mean_b(alpha[b])
// ---------------------------------------------------------------------------
__global__ void reduce_kernel(const float* __restrict__ alpha, float* __restrict__ out)
{
    const int tid = threadIdx.x;
    float v = (tid < B_) ? alpha[tid] : 0.f;
#pragma unroll
    for (int m = 16; m >= 1; m >>= 1) v += __shfl_xor(v, m);
    if (tid == 0) out[0] = -v / (float)B_;
}

// ---------------------------------------------------------------------------
extern "C" void kernel_launch(void* const* d_in, const int* in_sizes, int n_in,
                              void* d_out, int out_size, void* d_ws, size_t ws_size,
                              hipStream_t stream)
{
    const float* mu_logvar = (const float*)d_in[0];
    const float* melspec   = (const float*)d_in[1];
    const int*   tlen      = (const int*)d_in[2];
    const int*   mlen      = (const int*)d_in[3];
    float* out = (float*)d_out;
    float* ws  = (float*)d_ws;

    // ws layout (floats)
    const size_t IV_OFF    = 0;                        // 32*80*256 = 655360
    const size_t M2_OFF    = 655360;                   // 655360
    const size_t S_OFF     = 1310720;                  // 8192
    const size_t ALPHA_OFF = 1318912;                  // 32
    const size_t LPT_OFF   = 1318944;                  // 16,777,216 + pad
    const size_t LPT_ELEMS = (size_t)B_ * MEL * TXT;
    const size_t LPT_PAD   = (size_t)16 * TXT;         // 16 rows prefetch slack

    float* IV    = ws + IV_OFF;
    float* M2    = ws + M2_OFF;
    float* S     = ws + S_OFF;
    float* alpha = ws + ALPHA_OFF;
    float* lpT   = ws + LPT_OFF;

    const bool use_lpT = ws_size >= (LPT_OFF + LPT_ELEMS + LPT_PAD) * sizeof(float);

    precompute_kernel<<<dim3(B_), dim3(256), 0, stream>>>(mu_logvar, IV, M2, S);

    logprob_kernel<<<dim3(MEL / 128, TXT / 64, B_), dim3(256), 0, stream>>>(
        melspec, IV, M2, S, out + 1, lpT, use_lpT ? 1 : 0);

    if (use_lpT) {
        dp_kernel<<<dim3(B_), dim3(64), 0, stream>>>(lpT, tlen, mlen, alpha);
    } else {
        dp_kernel_fallback<<<dim3(B_), dim3(256), 0, stream>>>(out + 1, tlen, mlen, alpha);
    }

    reduce_kernel<<<dim3(1), dim3(64), 0, stream>>>(alpha, out);
}

// Round 4
// 437.501 us; speedup vs baseline: 1.1993x; 1.1993x over previous
//
#include <hip/hip_runtime.h>
#include <cstddef>
#include <cstdint>

#define NEGV -1e30f

constexpr int B_    = 32;
constexpr int TXT   = 256;
constexpr int MEL   = 2048;
constexpr int NMEL  = 80;

// base-2 domain constants for the DP (lpT is stored pre-scaled by 1/ln2)
#define INV_LN2 1.4426950408889634f
#define LN2     0.6931471805599453f

// ---------------------------------------------------------------------------
// Kernel P: per (b,j): iv[c]=exp(-logvar), m2[c]=2*mu*iv, s = sum(mu^2*iv + logvar)
// ---------------------------------------------------------------------------
__global__ __launch_bounds__(256) void precompute_kernel(
    const float* __restrict__ mu_logvar,
    float* __restrict__ IV, float* __restrict__ M2, float* __restrict__ S)
{
    const int b = blockIdx.x;
    const int j = threadIdx.x;
    const float* row = mu_logvar + (size_t)(b * TXT + j) * (2 * NMEL);
    float s = 0.f;
    for (int c = 0; c < NMEL; ++c) {
        float mu = row[c];
        float lv = row[NMEL + c];
        float iv = expf(-lv);
        IV[(b * NMEL + c) * TXT + j] = iv;
        M2[(b * NMEL + c) * TXT + j] = 2.0f * mu * iv;
        s += mu * mu * iv + lv;
    }
    S[b * TXT + j] = s;
}

// ---------------------------------------------------------------------------
// Kernel 1: log_prob. Tile 64 j x 128 t per block (256 threads).
// out1 gets exact ln-domain values; lpT gets the same values scaled by
// 1/ln2 so the DP can run in base-2 (native v_exp/v_log, no mul by 1.4427).
// ---------------------------------------------------------------------------
__global__ __launch_bounds__(256) void logprob_kernel(
    const float* __restrict__ mel,
    const float* __restrict__ IV, const float* __restrict__ M2,
    const float* __restrict__ S,
    float* __restrict__ out1,          // d_out + 1 (log_prob region)
    float* __restrict__ lpT,           // ws transposed copy [b][t][j], scaled 1/ln2
    int write_lpT)
{
    const int tt0 = blockIdx.x * 128;
    const int j0  = blockIdx.y * 64;
    const int b   = blockIdx.z;
    const int tx  = threadIdx.x & 15;
    const int ty  = threadIdx.x >> 4;

    __shared__ union SM {
        struct { float IV[NMEL][64]; float M2[NMEL][64]; } stage;
        float V[64][132];
    } sm;

    for (int idx = threadIdx.x; idx < NMEL * 64; idx += 256) {
        int c  = idx >> 6;
        int jj = idx & 63;
        sm.stage.IV[c][jj] = IV[(b * NMEL + c) * TXT + j0 + jj];
        sm.stage.M2[c][jj] = M2[(b * NMEL + c) * TXT + j0 + jj];
    }
    __syncthreads();

    float acc[4][8];
#pragma unroll
    for (int a = 0; a < 4; ++a)
#pragma unroll
        for (int d = 0; d < 8; ++d) acc[a][d] = 0.f;

    const float* melb = mel + (size_t)b * NMEL * MEL + tt0 + tx;

#pragma unroll 2
    for (int c = 0; c < NMEL; ++c) {
        float x[8];
#pragma unroll
        for (int d = 0; d < 8; ++d) x[d] = melb[(size_t)c * MEL + 16 * d];
        float4 iv = *(const float4*)&sm.stage.IV[c][ty * 4];
        float4 m2 = *(const float4*)&sm.stage.M2[c][ty * 4];
        float ivr[4] = {iv.x, iv.y, iv.z, iv.w};
        float m2r[4] = {m2.x, m2.y, m2.z, m2.w};
#pragma unroll
        for (int a = 0; a < 4; ++a) {
#pragma unroll
            for (int d = 0; d < 8; ++d) {
                float tmp = fmaf(ivr[a], x[d], -m2r[a]);
                acc[a][d] = fmaf(tmp, x[d], acc[a][d]);
            }
        }
    }

    const float c0 = -0.5f / (float)NMEL;
    float4 sj = *(const float4*)&S[b * TXT + j0 + ty * 4];
    float sjr[4] = {sj.x, sj.y, sj.z, sj.w};

    __syncthreads();   // everyone done reading stage.IV/stage.M2
#pragma unroll
    for (int a = 0; a < 4; ++a) {
        const int jl = ty * 4 + a;
#pragma unroll
        for (int d = 0; d < 8; ++d) {
            sm.V[jl][tx + 16 * d] = c0 * (acc[a][d] + sjr[a]);
        }
    }
    __syncthreads();

    const int tid = threadIdx.x;

    {
        const int t4 = (tid & 31) * 4;
        const int jb = tid >> 5;
#pragma unroll
        for (int k = 0; k < 8; ++k) {
            const int jl = jb + 8 * k;
            float4 v = *(const float4*)&sm.V[jl][t4];
            *(float4*)&out1[(size_t)(b * TXT + j0 + jl) * MEL + tt0 + t4] = v;
        }
    }

    if (write_lpT) {
        const int j4 = (tid & 15) * 4;
        const int tb = tid >> 4;
#pragma unroll
        for (int k = 0; k < 8; ++k) {
            const int tl = tb + 16 * k;
            float4 v;
            v.x = sm.V[j4 + 0][tl] * INV_LN2;
            v.y = sm.V[j4 + 1][tl] * INV_LN2;
            v.z = sm.V[j4 + 2][tl] * INV_LN2;
            v.w = sm.V[j4 + 3][tl] * INV_LN2;
            *(float4*)&lpT[((size_t)b * MEL + tt0 + tl) * TXT + j0 + j4] = v;
        }
    }
}

// ---------------------------------------------------------------------------
// DP kernel v5b: async prefetch lands in LDS (global_load_lds), not registers.
// (v4's register-resident asm loads raced: regalloc copies of in-flight dest
// regs are invisible to s_waitcnt.) With LDS as the DMA target, no
// architectural reg is written behind the compiler's back; ds_reads are plain
// loads so SIInsertWaitcnts (post-RA) protects every use. Manual duty:
// counted vmcnt (asm + "memory" + sched_barrier) before reading a ring row.
//   ring: 32 rows x 1KiB LDS, DMA depth 16 rows (~3 groups slack > HBM lat)
//   group of 4 t-steps: issue 4 DMAs -> vmcnt(12) -> ds_read next 4 rows into
//   a register double-buffer -> 4x DP_CORE on current rows.
// DP runs in base-2 (lpT pre-scaled): exp2f/__log2f are native v_exp/v_log.
// ---------------------------------------------------------------------------
typedef float f32x4 __attribute__((ext_vector_type(4)));

__device__ __forceinline__ float wave_ror1(float x) {
    int xi = __float_as_int(x);
    int r  = __builtin_amdgcn_update_dpp(xi, xi, 0x13C /*wave_ror:1*/, 0xF, 0xF, false);
    return __int_as_float(r);
}

// base-2 logaddexp: exact rescale of ln-domain lse (a,b already in 1/ln2 units)
// NOTE: __exp2f does not exist in HIP headers (R3 compile fail); exp2f lowers
// to native v_exp_f32 on gfx950.
__device__ __forceinline__ float lse2b(float a, float b) {
    float mx = fmaxf(a, b);
    float d  = -fabsf(a - b);
    return mx + __log2f(1.0f + exp2f(d));
}

__global__ __launch_bounds__(64, 1) void dp_kernel(
    const float* __restrict__ lpT,
    const int* __restrict__ tlen, const int* __restrict__ mlen,
    float* __restrict__ alpha)
{
    const int b = blockIdx.x;
    const int l = threadIdx.x;          // 0..63

    const int tl   = tlen[b];
    const int ml   = mlen[b];
    const int tmax = ml - 1;            // >= 1023 for this shape
    const int jt   = tl - 1;
    const float out_scale = LN2 / (float)ml;   // back to ln-domain + /ml

    const float* sbase = lpT + (size_t)b * MEL * TXT;
    const bool z = (l == 0);

    __shared__ float ring[32][256];     // 32 rows x 1024B

    // t = 0 init (plain load; row 0 of lpT is base-2 scaled like all of lpT)
    f32x4 ld0 = *(const f32x4*)(sbase + l * 4);
    float c0 = z ? ld0[0] : NEGV;
    float c1 = NEGV, c2 = NEGV, c3 = NEGV;

    if (tmax <= 0) {
        const int lf = jt >> 2, ef = jt & 3;
        float v = (ef == 0) ? c0 : NEGV;
        if (l == lf) alpha[b] = v * out_scale;
        return;
    }

    // keep ld0's compiler vmcnt(0) above all DMA issues
    __builtin_amdgcn_sched_barrier(0);

    // issue DMA for row r -> ring[r & 31]; lane l supplies 16B at col l*4
#define ISSUE(R)                                                              \
    __builtin_amdgcn_global_load_lds(                                         \
        (const __attribute__((address_space(1))) void*)(sbase + (size_t)(R) * TXT + l * 4), \
        (__attribute__((address_space(3))) void*)&ring[(R) & 31][0],          \
        16, 0, 0)

    // prologue: rows 1..16 in flight (depth D=16)
#pragma unroll
    for (int r = 1; r <= 16; ++r) ISSUE(r);

    // rows 1..4 ready -> load cur
    asm volatile("s_waitcnt vmcnt(12)" ::: "memory");
    __builtin_amdgcn_sched_barrier(0);
    f32x4 cur0 = *(const f32x4*)&ring[1][l * 4];
    f32x4 cur1 = *(const f32x4*)&ring[2][l * 4];
    f32x4 cur2 = *(const f32x4*)&ring[3][l * 4];
    f32x4 cur3 = *(const f32x4*)&ring[4][l * 4];

#define DP_CORE(LP)                                            \
    {                                                          \
        float sw = wave_ror1(c3);                              \
        sw = z ? NEGV : sw;                                    \
        float n0 = lse2b(c0, sw) + (LP)[0];                    \
        float n1 = lse2b(c1, c0) + (LP)[1];                    \
        float n2 = lse2b(c2, c1) + (LP)[2];                    \
        float n3 = lse2b(c3, c2) + (LP)[3];                    \
        c0 = n0; c1 = n1; c2 = n2; c3 = n3;                    \
    }

    // main loop: compute rows t..t+3, read rows t+4..t+7, issue rows t+16..t+19
    // invariant at entry: DMAs issued through row t+15, retired through t+3.
    int t = 1;
    for (; t + 7 <= tmax; t += 4) {
        ISSUE(t + 16); ISSUE(t + 17); ISSUE(t + 18); ISSUE(t + 19);
        // issued through t+19; vmcnt(12) -> retired through (t+19)-12 = t+7
        asm volatile("s_waitcnt vmcnt(12)" ::: "memory");
        __builtin_amdgcn_sched_barrier(0);
        f32x4 n0v = *(const f32x4*)&ring[(t + 4) & 31][l * 4];
        f32x4 n1v = *(const f32x4*)&ring[(t + 5) & 31][l * 4];
        f32x4 n2v = *(const f32x4*)&ring[(t + 6) & 31][l * 4];
        f32x4 n3v = *(const f32x4*)&ring[(t + 7) & 31][l * 4];
        DP_CORE(cur0); DP_CORE(cur1); DP_CORE(cur2); DP_CORE(cur3);
        cur0 = n0v; cur1 = n1v; cur2 = n2v; cur3 = n3v;
    }

    // tail: 4..7 rows remain (t..tmax); cur holds rows t..t+3 (all valid,
    // t <= tmax-3). Rows t+4..tmax are in the ring (issued through t+15).
    asm volatile("s_waitcnt vmcnt(0)" ::: "memory");
    __builtin_amdgcn_sched_barrier(0);

    DP_CORE(cur0);
    if (t + 1 <= tmax) DP_CORE(cur1);
    if (t + 2 <= tmax) DP_CORE(cur2);
    if (t + 3 <= tmax) DP_CORE(cur3);
#pragma unroll
    for (int k = 4; k <= 6; ++k) {
        if (t + k <= tmax) {
            f32x4 rr = *(const f32x4*)&ring[(t + k) & 31][l * 4];
            DP_CORE(rr);
        }
    }

#undef DP_CORE
#undef ISSUE

    const int lf = jt >> 2;
    const int ef = jt & 3;
    float v = (ef == 0) ? c0 : (ef == 1) ? c1 : (ef == 2) ? c2 : c3;
    if (l == lf) alpha[b] = v * out_scale;
}

// ---------------------------------------------------------------------------
// DP fallback (un-transposed, ln-domain reads from out1) — safety net.
// ---------------------------------------------------------------------------
__global__ __launch_bounds__(256) void dp_kernel_fallback(
    const float* __restrict__ lp,
    const int* __restrict__ tlen, const int* __restrict__ mlen,
    float* __restrict__ alpha)
{
    const int b    = blockIdx.x;
    const int j    = threadIdx.x;
    const int lane = j & 63;
    const int w    = j >> 6;

    const int tl   = tlen[b];
    const int ml   = mlen[b];
    const int tmax = ml - 1;
    const int jt   = tl - 1;
    const float inv_ml = 1.0f / (float)ml;

    __shared__ float bnd[2][4];
    if (threadIdx.x < 8) bnd[threadIdx.x >> 2][threadIdx.x & 3] = NEGV;
    __syncthreads();

    float cur = (j == 0) ? lp[(size_t)(b * TXT) * MEL] : NEGV;
    if (tmax == 0) {
        if (j == jt) alpha[b] = cur * inv_ml;
        return;
    }
    int p = 0;
    for (int t = 1; t <= tmax; ++t) {
        float lpc = lp[((size_t)(b * TXT + j)) * MEL + t];
        float sh = __shfl_up(cur, 1);
        if (lane == 0) sh = (w > 0) ? bnd[p][w - 1] : NEGV;
        float mx = fmaxf(cur, sh);
        float dd = fminf(cur, sh) - mx;
        float nv = mx + __logf(1.0f + __expf(dd)) + lpc;
        if (lane == 63) bnd[p ^ 1][w] = nv;
        if (t == tmax && j == jt) alpha[b] = nv * inv_ml;
        cur = nv;
        __syncthreads();
        p ^= 1;
    }
}

// ---------------------------------------------------------------------------
// Reduce: loss = -mean_b(alpha[b])
// ---------------------------------------------------------------------------
__global__ void reduce_kernel(const float* __restrict__ alpha, float* __restrict__ out)
{
    const int tid = threadIdx.x;
    float v = (tid < B_) ? alpha[tid] : 0.f;
#pragma unroll
    for (int m = 16; m >= 1; m >>= 1) v += __shfl_xor(v, m);
    if (tid == 0) out[0] = -v / (float)B_;
}

// ---------------------------------------------------------------------------
extern "C" void kernel_launch(void* const* d_in, const int* in_sizes, int n_in,
                              void* d_out, int out_size, void* d_ws, size_t ws_size,
                              hipStream_t stream)
{
    const float* mu_logvar = (const float*)d_in[0];
    const float* melspec   = (const float*)d_in[1];
    const int*   tlen      = (const int*)d_in[2];
    const int*   mlen      = (const int*)d_in[3];
    float* out = (float*)d_out;
    float* ws  = (float*)d_ws;

    // ws layout (floats)
    const size_t IV_OFF    = 0;                        // 32*80*256 = 655360
    const size_t M2_OFF    = 655360;                   // 655360
    const size_t S_OFF     = 1310720;                  // 8192
    const size_t ALPHA_OFF = 1318912;                  // 32
    const size_t LPT_OFF   = 1318944;                  // 16,777,216 + pad
    const size_t LPT_ELEMS = (size_t)B_ * MEL * TXT;
    const size_t LPT_PAD   = (size_t)16 * TXT;         // 16 rows prefetch slack
                                                       // (max issued row = tmax+12 <= 2059 < 2064)

    float* IV    = ws + IV_OFF;
    float* M2    = ws + M2_OFF;
    float* S     = ws + S_OFF;
    float* alpha = ws + ALPHA_OFF;
    float* lpT   = ws + LPT_OFF;

    const bool use_lpT = ws_size >= (LPT_OFF + LPT_ELEMS + LPT_PAD) * sizeof(float);

    precompute_kernel<<<dim3(B_), dim3(256), 0, stream>>>(mu_logvar, IV, M2, S);

    logprob_kernel<<<dim3(MEL / 128, TXT / 64, B_), dim3(256), 0, stream>>>(
        melspec, IV, M2, S, out + 1, lpT, use_lpT ? 1 : 0);

    if (use_lpT) {
        dp_kernel<<<dim3(B_), dim3(64), 0, stream>>>(lpT, tlen, mlen, alpha);
    } else {
        dp_kernel_fallback<<<dim3(B_), dim3(256), 0, stream>>>(out + 1, tlen, mlen, alpha);
    }

    reduce_kernel<<<dim3(1), dim3(64), 0, stream>>>(alpha, out);
}

// Round 5
// 357.620 us; speedup vs baseline: 1.4672x; 1.2234x over previous
//
#include <hip/hip_runtime.h>
#include <cstddef>
#include <cstdint>

#define NEGV -1e30f

constexpr int B_    = 32;
constexpr int TXT   = 256;
constexpr int MEL   = 2048;
constexpr int NMEL  = 80;

// base-2 domain constants for the DP (lpT is stored pre-scaled by 1/ln2)
#define INV_LN2 1.4426950408889634f
#define LN2     0.6931471805599453f

// ---------------------------------------------------------------------------
// Kernel P: per (b,j): iv[c]=exp(-logvar), m2[c]=2*mu*iv, s = sum(mu^2*iv + logvar)
// ---------------------------------------------------------------------------
__global__ __launch_bounds__(256) void precompute_kernel(
    const float* __restrict__ mu_logvar,
    float* __restrict__ IV, float* __restrict__ M2, float* __restrict__ S)
{
    const int b = blockIdx.x;
    const int j = threadIdx.x;
    const float* row = mu_logvar + (size_t)(b * TXT + j) * (2 * NMEL);
    float s = 0.f;
    for (int c = 0; c < NMEL; ++c) {
        float mu = row[c];
        float lv = row[NMEL + c];
        float iv = expf(-lv);
        IV[(b * NMEL + c) * TXT + j] = iv;
        M2[(b * NMEL + c) * TXT + j] = 2.0f * mu * iv;
        s += mu * mu * iv + lv;
    }
    S[b * TXT + j] = s;
}

// ---------------------------------------------------------------------------
// Kernel 1: log_prob. Tile 64 j x 128 t per block (256 threads).
// out1 gets exact ln-domain values; lpT gets the same values scaled by
// 1/ln2 so the DP can run in base-2 (native v_exp/v_log, no mul by 1.4427).
// ---------------------------------------------------------------------------
__global__ __launch_bounds__(256) void logprob_kernel(
    const float* __restrict__ mel,
    const float* __restrict__ IV, const float* __restrict__ M2,
    const float* __restrict__ S,
    float* __restrict__ out1,          // d_out + 1 (log_prob region)
    float* __restrict__ lpT,           // ws transposed copy [b][t][j], scaled 1/ln2
    int write_lpT)
{
    const int tt0 = blockIdx.x * 128;
    const int j0  = blockIdx.y * 64;
    const int b   = blockIdx.z;
    const int tx  = threadIdx.x & 15;
    const int ty  = threadIdx.x >> 4;

    __shared__ union SM {
        struct { float IV[NMEL][64]; float M2[NMEL][64]; } stage;
        float V[64][132];
    } sm;

    for (int idx = threadIdx.x; idx < NMEL * 64; idx += 256) {
        int c  = idx >> 6;
        int jj = idx & 63;
        sm.stage.IV[c][jj] = IV[(b * NMEL + c) * TXT + j0 + jj];
        sm.stage.M2[c][jj] = M2[(b * NMEL + c) * TXT + j0 + jj];
    }
    __syncthreads();

    float acc[4][8];
#pragma unroll
    for (int a = 0; a < 4; ++a)
#pragma unroll
        for (int d = 0; d < 8; ++d) acc[a][d] = 0.f;

    const float* melb = mel + (size_t)b * NMEL * MEL + tt0 + tx;

#pragma unroll 2
    for (int c = 0; c < NMEL; ++c) {
        float x[8];
#pragma unroll
        for (int d = 0; d < 8; ++d) x[d] = melb[(size_t)c * MEL + 16 * d];
        float4 iv = *(const float4*)&sm.stage.IV[c][ty * 4];
        float4 m2 = *(const float4*)&sm.stage.M2[c][ty * 4];
        float ivr[4] = {iv.x, iv.y, iv.z, iv.w};
        float m2r[4] = {m2.x, m2.y, m2.z, m2.w};
#pragma unroll
        for (int a = 0; a < 4; ++a) {
#pragma unroll
            for (int d = 0; d < 8; ++d) {
                float tmp = fmaf(ivr[a], x[d], -m2r[a]);
                acc[a][d] = fmaf(tmp, x[d], acc[a][d]);
            }
        }
    }

    const float c0 = -0.5f / (float)NMEL;
    float4 sj = *(const float4*)&S[b * TXT + j0 + ty * 4];
    float sjr[4] = {sj.x, sj.y, sj.z, sj.w};

    __syncthreads();   // everyone done reading stage.IV/stage.M2
#pragma unroll
    for (int a = 0; a < 4; ++a) {
        const int jl = ty * 4 + a;
#pragma unroll
        for (int d = 0; d < 8; ++d) {
            sm.V[jl][tx + 16 * d] = c0 * (acc[a][d] + sjr[a]);
        }
    }
    __syncthreads();

    const int tid = threadIdx.x;

    {
        const int t4 = (tid & 31) * 4;
        const int jb = tid >> 5;
#pragma unroll
        for (int k = 0; k < 8; ++k) {
            const int jl = jb + 8 * k;
            float4 v = *(const float4*)&sm.V[jl][t4];
            *(float4*)&out1[(size_t)(b * TXT + j0 + jl) * MEL + tt0 + t4] = v;
        }
    }

    if (write_lpT) {
        const int j4 = (tid & 15) * 4;
        const int tb = tid >> 4;
#pragma unroll
        for (int k = 0; k < 8; ++k) {
            const int tl = tb + 16 * k;
            float4 v;
            v.x = sm.V[j4 + 0][tl] * INV_LN2;
            v.y = sm.V[j4 + 1][tl] * INV_LN2;
            v.z = sm.V[j4 + 2][tl] * INV_LN2;
            v.w = sm.V[j4 + 3][tl] * INV_LN2;
            *(float4*)&lpT[((size_t)b * MEL + tt0 + tl) * TXT + j0 + j4] = v;
        }
    }
}

// ---------------------------------------------------------------------------
// DP kernel v6: R4 counters showed 295 cy/step with ~177 cy of issue (active-
// SIMD VALUBusy ~60%) vs a ~108 cy hand count — the excess matches exp2f's
// OCML wrapper (~8 instrs of denorm/range fixup per call, 4 calls/step).
// Change: single-instruction v_exp_f32/v_log_f32 via builtins (asm fallback;
// d <= 0 always, so raw v_exp is exact in our domain), and fold +lp into the
// mx add so it runs parallel to the exp2->log2 chain (serial chain -1 op).
// Prefetch structure (LDS ring + counted vmcnt) unchanged from v5b.
// ---------------------------------------------------------------------------
typedef float f32x4 __attribute__((ext_vector_type(4)));

__device__ __forceinline__ float wave_ror1(float x) {
    int xi = __float_as_int(x);
    int r  = __builtin_amdgcn_update_dpp(xi, xi, 0x13C /*wave_ror:1*/, 0xF, 0xF, false);
    return __int_as_float(r);
}

// native base-2 exp: v_exp_f32, no OCML wrapper
__device__ __forceinline__ float exp2_nat(float x) {
#if __has_builtin(__builtin_amdgcn_exp2f)
    return __builtin_amdgcn_exp2f(x);
#else
    float r; asm("v_exp_f32 %0, %1" : "=v"(r) : "v"(x)); return r;
#endif
}

// native base-2 log: v_log_f32
__device__ __forceinline__ float log2_nat(float x) {
#if __has_builtin(__builtin_amdgcn_logf)
    return __builtin_amdgcn_logf(x);
#else
    float r; asm("v_log_f32 %0, %1" : "=v"(r) : "v"(x)); return r;
#endif
}

// base-2 logaddexp + lp, lp folded into the parallel (mx) side of the chain:
// chain = fmax -> sub(-|.|) -> exp2 -> add -> log2 -> add   (base = mx+lp runs
// alongside). Inputs are in 1/ln2 units.
__device__ __forceinline__ float lse2b_lp(float a, float b, float lp) {
    float mx   = fmaxf(a, b);
    float d    = -fabsf(a - b);
    float base = mx + lp;
    return base + log2_nat(1.0f + exp2_nat(d));
}

__global__ __launch_bounds__(64, 1) void dp_kernel(
    const float* __restrict__ lpT,
    const int* __restrict__ tlen, const int* __restrict__ mlen,
    float* __restrict__ alpha)
{
    const int b = blockIdx.x;
    const int l = threadIdx.x;          // 0..63

    const int tl   = tlen[b];
    const int ml   = mlen[b];
    const int tmax = ml - 1;            // >= 1023 for this shape
    const int jt   = tl - 1;
    const float out_scale = LN2 / (float)ml;   // back to ln-domain + /ml

    const float* sbase = lpT + (size_t)b * MEL * TXT;
    const bool z = (l == 0);

    __shared__ float ring[32][256];     // 32 rows x 1024B

    // t = 0 init (plain load; row 0 of lpT is base-2 scaled like all of lpT)
    f32x4 ld0 = *(const f32x4*)(sbase + l * 4);
    float c0 = z ? ld0[0] : NEGV;
    float c1 = NEGV, c2 = NEGV, c3 = NEGV;

    if (tmax <= 0) {
        const int lf = jt >> 2, ef = jt & 3;
        float v = (ef == 0) ? c0 : NEGV;
        if (l == lf) alpha[b] = v * out_scale;
        return;
    }

    // keep ld0's compiler vmcnt(0) above all DMA issues
    __builtin_amdgcn_sched_barrier(0);

    // issue DMA for row r -> ring[r & 31]; lane l supplies 16B at col l*4
#define ISSUE(R)                                                              \
    __builtin_amdgcn_global_load_lds(                                         \
        (const __attribute__((address_space(1))) void*)(sbase + (size_t)(R) * TXT + l * 4), \
        (__attribute__((address_space(3))) void*)&ring[(R) & 31][0],          \
        16, 0, 0)

    // prologue: rows 1..16 in flight (depth D=16)
#pragma unroll
    for (int r = 1; r <= 16; ++r) ISSUE(r);

    // rows 1..4 ready -> load cur
    asm volatile("s_waitcnt vmcnt(12)" ::: "memory");
    __builtin_amdgcn_sched_barrier(0);
    f32x4 cur0 = *(const f32x4*)&ring[1][l * 4];
    f32x4 cur1 = *(const f32x4*)&ring[2][l * 4];
    f32x4 cur2 = *(const f32x4*)&ring[3][l * 4];
    f32x4 cur3 = *(const f32x4*)&ring[4][l * 4];

#define DP_CORE(LP)                                            \
    {                                                          \
        float sw = wave_ror1(c3);                              \
        sw = z ? NEGV : sw;                                    \
        float n0 = lse2b_lp(c0, sw, (LP)[0]);                  \
        float n1 = lse2b_lp(c1, c0, (LP)[1]);                  \
        float n2 = lse2b_lp(c2, c1, (LP)[2]);                  \
        float n3 = lse2b_lp(c3, c2, (LP)[3]);                  \
        c0 = n0; c1 = n1; c2 = n2; c3 = n3;                    \
    }

    // main loop: compute rows t..t+3, read rows t+4..t+7, issue rows t+16..t+19
    // invariant at entry: DMAs issued through row t+15, retired through t+3.
    int t = 1;
    for (; t + 7 <= tmax; t += 4) {
        ISSUE(t + 16); ISSUE(t + 17); ISSUE(t + 18); ISSUE(t + 19);
        // issued through t+19; vmcnt(12) -> retired through (t+19)-12 = t+7
        asm volatile("s_waitcnt vmcnt(12)" ::: "memory");
        __builtin_amdgcn_sched_barrier(0);
        f32x4 n0v = *(const f32x4*)&ring[(t + 4) & 31][l * 4];
        f32x4 n1v = *(const f32x4*)&ring[(t + 5) & 31][l * 4];
        f32x4 n2v = *(const f32x4*)&ring[(t + 6) & 31][l * 4];
        f32x4 n3v = *(const f32x4*)&ring[(t + 7) & 31][l * 4];
        DP_CORE(cur0); DP_CORE(cur1); DP_CORE(cur2); DP_CORE(cur3);
        cur0 = n0v; cur1 = n1v; cur2 = n2v; cur3 = n3v;
    }

    // tail: 4..7 rows remain (t..tmax); cur holds rows t..t+3 (all valid,
    // t <= tmax-3). Rows t+4..tmax are in the ring (issued through t+15).
    asm volatile("s_waitcnt vmcnt(0)" ::: "memory");
    __builtin_amdgcn_sched_barrier(0);

    DP_CORE(cur0);
    if (t + 1 <= tmax) DP_CORE(cur1);
    if (t + 2 <= tmax) DP_CORE(cur2);
    if (t + 3 <= tmax) DP_CORE(cur3);
#pragma unroll
    for (int k = 4; k <= 6; ++k) {
        if (t + k <= tmax) {
            f32x4 rr = *(const f32x4*)&ring[(t + k) & 31][l * 4];
            DP_CORE(rr);
        }
    }

#undef DP_CORE
#undef ISSUE

    const int lf = jt >> 2;
    const int ef = jt & 3;
    float v = (ef == 0) ? c0 : (ef == 1) ? c1 : (ef == 2) ? c2 : c3;
    if (l == lf) alpha[b] = v * out_scale;
}

// ---------------------------------------------------------------------------
// DP fallback (un-transposed, ln-domain reads from out1) — safety net.
// ---------------------------------------------------------------------------
__global__ __launch_bounds__(256) void dp_kernel_fallback(
    const float* __restrict__ lp,
    const int* __restrict__ tlen, const int* __restrict__ mlen,
    float* __restrict__ alpha)
{
    const int b    = blockIdx.x;
    const int j    = threadIdx.x;
    const int lane = j & 63;
    const int w    = j >> 6;

    const int tl   = tlen[b];
    const int ml   = mlen[b];
    const int tmax = ml - 1;
    const int jt   = tl - 1;
    const float inv_ml = 1.0f / (float)ml;

    __shared__ float bnd[2][4];
    if (threadIdx.x < 8) bnd[threadIdx.x >> 2][threadIdx.x & 3] = NEGV;
    __syncthreads();

    float cur = (j == 0) ? lp[(size_t)(b * TXT) * MEL] : NEGV;
    if (tmax == 0) {
        if (j == jt) alpha[b] = cur * inv_ml;
        return;
    }
    int p = 0;
    for (int t = 1; t <= tmax; ++t) {
        float lpc = lp[((size_t)(b * TXT + j)) * MEL + t];
        float sh = __shfl_up(cur, 1);
        if (lane == 0) sh = (w > 0) ? bnd[p][w - 1] : NEGV;
        float mx = fmaxf(cur, sh);
        float dd = fminf(cur, sh) - mx;
        float nv = mx + __logf(1.0f + __expf(dd)) + lpc;
        if (lane == 63) bnd[p ^ 1][w] = nv;
        if (t == tmax && j == jt) alpha[b] = nv * inv_ml;
        cur = nv;
        __syncthreads();
        p ^= 1;
    }
}

// ---------------------------------------------------------------------------
// Reduce: loss = -mean_b(alpha[b])
// ---------------------------------------------------------------------------
__global__ void reduce_kernel(const float* __restrict__ alpha, float* __restrict__ out)
{
    const int tid = threadIdx.x;
    float v = (tid < B_) ? alpha[tid] : 0.f;
#pragma unroll
    for (int m = 16; m >= 1; m >>= 1) v += __shfl_xor(v, m);
    if (tid == 0) out[0] = -v / (float)B_;
}

// ---------------------------------------------------------------------------
extern "C" void kernel_launch(void* const* d_in, const int* in_sizes, int n_in,
                              void* d_out, int out_size, void* d_ws, size_t ws_size,
                              hipStream_t stream)
{
    const float* mu_logvar = (const float*)d_in[0];
    const float* melspec   = (const float*)d_in[1];
    const int*   tlen      = (const int*)d_in[2];
    const int*   mlen      = (const int*)d_in[3];
    float* out = (float*)d_out;
    float* ws  = (float*)d_ws;

    // ws layout (floats)
    const size_t IV_OFF    = 0;                        // 32*80*256 = 655360
    const size_t M2_OFF    = 655360;                   // 655360
    const size_t S_OFF     = 1310720;                  // 8192
    const size_t ALPHA_OFF = 1318912;                  // 32
    const size_t LPT_OFF   = 1318944;                  // 16,777,216 + pad
    const size_t LPT_ELEMS = (size_t)B_ * MEL * TXT;
    const size_t LPT_PAD   = (size_t)16 * TXT;         // 16 rows prefetch slack
                                                       // (max issued row = tmax+12 <= 2059 < 2064)

    float* IV    = ws + IV_OFF;
    float* M2    = ws + M2_OFF;
    float* S     = ws + S_OFF;
    float* alpha = ws + ALPHA_OFF;
    float* lpT   = ws + LPT_OFF;

    const bool use_lpT = ws_size >= (LPT_OFF + LPT_ELEMS + LPT_PAD) * sizeof(float);

    precompute_kernel<<<dim3(B_), dim3(256), 0, stream>>>(mu_logvar, IV, M2, S);

    logprob_kernel<<<dim3(MEL / 128, TXT / 64, B_), dim3(256), 0, stream>>>(
        melspec, IV, M2, S, out + 1, lpT, use_lpT ? 1 : 0);

    if (use_lpT) {
        dp_kernel<<<dim3(B_), dim3(64), 0, stream>>>(lpT, tlen, mlen, alpha);
    } else {
        dp_kernel_fallback<<<dim3(B_), dim3(256), 0, stream>>>(out + 1, tlen, mlen, alpha);
    }

    reduce_kernel<<<dim3(1), dim3(64), 0, stream>>>(alpha, out);
}

// Round 6
// 315.203 us; speedup vs baseline: 1.6647x; 1.1346x over previous
//
#include <hip/hip_runtime.h>
#include <cstddef>
#include <cstdint>

#define NEGV -1e30f

constexpr int B_    = 32;
constexpr int TXT   = 256;
constexpr int MEL   = 2048;
constexpr int NMEL  = 80;

// base-2 / linear domain constants
#define INV_LN2 1.4426950408889634f
#define LN2     0.6931471805599453f
#define M_DEAD  (-(1 << 30))          // "lane has zero mass" scale marker

// ---------------------------------------------------------------------------
// helpers (used by logprob epilogue and DP)
// ---------------------------------------------------------------------------
typedef float f32x4 __attribute__((ext_vector_type(4)));

__device__ __forceinline__ float wave_ror1_f(float x) {
    int xi = __float_as_int(x);
    int r  = __builtin_amdgcn_update_dpp(xi, xi, 0x13C /*wave_ror:1*/, 0xF, 0xF, false);
    return __int_as_float(r);
}
__device__ __forceinline__ int wave_ror1_i(int x) {
    return __builtin_amdgcn_update_dpp(x, x, 0x13C /*wave_ror:1*/, 0xF, 0xF, false);
}

// native base-2 exp: single v_exp_f32 (verified compiles, R5)
__device__ __forceinline__ float exp2_nat(float x) {
#if __has_builtin(__builtin_amdgcn_exp2f)
    return __builtin_amdgcn_exp2f(x);
#else
    float r; asm("v_exp_f32 %0, %1" : "=v"(r) : "v"(x)); return r;
#endif
}
// native base-2 log: single v_log_f32
__device__ __forceinline__ float log2_nat(float x) {
#if __has_builtin(__builtin_amdgcn_logf)
    return __builtin_amdgcn_logf(x);
#else
    float r; asm("v_log_f32 %0, %1" : "=v"(r) : "v"(x)); return r;
#endif
}
// exact x * 2^n: single v_ldexp_f32 (exact for any n; saturates to 0 for huge -n)
__device__ __forceinline__ float ldexp_nat(float x, int n) {
#if __has_builtin(__builtin_amdgcn_ldexpf)
    return __builtin_amdgcn_ldexpf(x, n);
#else
    float r; asm("v_ldexp_f32 %0, %1, %2" : "=v"(r) : "v"(x), "v"(n)); return r;
#endif
}

// ---------------------------------------------------------------------------
// Kernel P: per (b,j): iv[c]=exp(-logvar), m2[c]=2*mu*iv, s = sum(mu^2*iv + logvar)
// ---------------------------------------------------------------------------
__global__ __launch_bounds__(256) void precompute_kernel(
    const float* __restrict__ mu_logvar,
    float* __restrict__ IV, float* __restrict__ M2, float* __restrict__ S)
{
    const int b = blockIdx.x;
    const int j = threadIdx.x;
    const float* row = mu_logvar + (size_t)(b * TXT + j) * (2 * NMEL);
    float s = 0.f;
    for (int c = 0; c < NMEL; ++c) {
        float mu = row[c];
        float lv = row[NMEL + c];
        float iv = expf(-lv);
        IV[(b * NMEL + c) * TXT + j] = iv;
        M2[(b * NMEL + c) * TXT + j] = 2.0f * mu * iv;
        s += mu * mu * iv + lv;
    }
    S[b * TXT + j] = s;
}

// ---------------------------------------------------------------------------
// Kernel 1: log_prob. Tile 64 j x 128 t per block (256 threads).
// out1 gets exact ln-domain values. lpT now stores p = exp(lp) (LINEAR
// probability factors, = 2^(lp/ln2)) so the serial DP needs ZERO
// transcendentals per step (R5 counters: 8 trans/step = 64 of 116 issue cy).
// exp2 here is massively parallel (32 per thread, v_exp_f32).
// ---------------------------------------------------------------------------
__global__ __launch_bounds__(256) void logprob_kernel(
    const float* __restrict__ mel,
    const float* __restrict__ IV, const float* __restrict__ M2,
    const float* __restrict__ S,
    float* __restrict__ out1,          // d_out + 1 (log_prob region)
    float* __restrict__ lpT,           // ws transposed copy [b][t][j] = exp(lp)
    int write_lpT)
{
    const int tt0 = blockIdx.x * 128;
    const int j0  = blockIdx.y * 64;
    const int b   = blockIdx.z;
    const int tx  = threadIdx.x & 15;
    const int ty  = threadIdx.x >> 4;

    __shared__ union SM {
        struct { float IV[NMEL][64]; float M2[NMEL][64]; } stage;
        float V[64][132];
    } sm;

    for (int idx = threadIdx.x; idx < NMEL * 64; idx += 256) {
        int c  = idx >> 6;
        int jj = idx & 63;
        sm.stage.IV[c][jj] = IV[(b * NMEL + c) * TXT + j0 + jj];
        sm.stage.M2[c][jj] = M2[(b * NMEL + c) * TXT + j0 + jj];
    }
    __syncthreads();

    float acc[4][8];
#pragma unroll
    for (int a = 0; a < 4; ++a)
#pragma unroll
        for (int d = 0; d < 8; ++d) acc[a][d] = 0.f;

    const float* melb = mel + (size_t)b * NMEL * MEL + tt0 + tx;

#pragma unroll 2
    for (int c = 0; c < NMEL; ++c) {
        float x[8];
#pragma unroll
        for (int d = 0; d < 8; ++d) x[d] = melb[(size_t)c * MEL + 16 * d];
        float4 iv = *(const float4*)&sm.stage.IV[c][ty * 4];
        float4 m2 = *(const float4*)&sm.stage.M2[c][ty * 4];
        float ivr[4] = {iv.x, iv.y, iv.z, iv.w};
        float m2r[4] = {m2.x, m2.y, m2.z, m2.w};
#pragma unroll
        for (int a = 0; a < 4; ++a) {
#pragma unroll
            for (int d = 0; d < 8; ++d) {
                float tmp = fmaf(ivr[a], x[d], -m2r[a]);
                acc[a][d] = fmaf(tmp, x[d], acc[a][d]);
            }
        }
    }

    const float c0 = -0.5f / (float)NMEL;
    float4 sj = *(const float4*)&S[b * TXT + j0 + ty * 4];
    float sjr[4] = {sj.x, sj.y, sj.z, sj.w};

    __syncthreads();   // everyone done reading stage.IV/stage.M2
#pragma unroll
    for (int a = 0; a < 4; ++a) {
        const int jl = ty * 4 + a;
#pragma unroll
        for (int d = 0; d < 8; ++d) {
            sm.V[jl][tx + 16 * d] = c0 * (acc[a][d] + sjr[a]);
        }
    }
    __syncthreads();

    const int tid = threadIdx.x;

    {
        const int t4 = (tid & 31) * 4;
        const int jb = tid >> 5;
#pragma unroll
        for (int k = 0; k < 8; ++k) {
            const int jl = jb + 8 * k;
            float4 v = *(const float4*)&sm.V[jl][t4];
            *(float4*)&out1[(size_t)(b * TXT + j0 + jl) * MEL + tt0 + t4] = v;
        }
    }

    if (write_lpT) {
        const int j4 = (tid & 15) * 4;
        const int tb = tid >> 4;
#pragma unroll
        for (int k = 0; k < 8; ++k) {
            const int tl = tb + 16 * k;
            float4 v;
            v.x = exp2_nat(sm.V[j4 + 0][tl] * INV_LN2);
            v.y = exp2_nat(sm.V[j4 + 1][tl] * INV_LN2);
            v.z = exp2_nat(sm.V[j4 + 2][tl] * INV_LN2);
            v.w = exp2_nat(sm.V[j4 + 3][tl] * INV_LN2);
            *(float4*)&lpT[((size_t)b * MEL + tt0 + tl) * TXT + j0 + j4] = v;
        }
    }
}

// ---------------------------------------------------------------------------
// DP kernel v7: LINEAR-domain DP (flash-attention style).
// State per lane: q0..q3 >= 0 (fp32) and integer scale M, with the EXACT
// invariant alpha[4l+i] = log2(q_i) + M (base-2). Step:
//     q'[j] = (q[j] + q[j-1]) * p[j]          (p precomputed in logprob)
// Scale handling (all exact ops: ldexp + int adds):
//  - boundary: neighbor passes (q3, M) via DPP; common scale Mc = max(M, Mb),
//    both shifts <= 0 -> ldexp never overflows; values < 2^-126 relative to
//    the dominant side flush to 0 (below fp32 lse contribution anyway).
//  - dead lanes carry M = M_DEAD so arriving mass adopts the live neighbor's
//    scale (wavefront can cross into untouched lanes at any t).
//  - lane-local renorm every 4-step group: exponent via bit-extract,
//    q *= 2^-ex, M += ex; all-zero lane -> M = M_DEAD.
// Zero transcendentals in the serial loop (R5: trans were 64/116 issue cy).
// Prefetch ring (32 rows x 1KiB LDS, depth 16, vmcnt(12)) unchanged from v5b.
// ---------------------------------------------------------------------------
__global__ __launch_bounds__(64, 1) void dp_kernel(
    const float* __restrict__ lpT,     // p = exp(lp), layout [b][t][j]
    const int* __restrict__ tlen, const int* __restrict__ mlen,
    float* __restrict__ alpha)
{
    const int b = blockIdx.x;
    const int l = threadIdx.x;          // 0..63

    const int tl   = tlen[b];
    const int ml   = mlen[b];
    const int tmax = ml - 1;            // >= 1023 for this shape
    const int jt   = tl - 1;
    const float out_scale = LN2 / (float)ml;   // base-2 -> ln, then /ml

    const float* sbase = lpT + (size_t)b * MEL * TXT;
    const bool z = (l == 0);

    __shared__ float ring[32][256];     // 32 rows x 1024B

    // t = 0 init: alpha0[0] = log(p00), alpha0[j>0] = -inf.
    f32x4 ld0 = *(const f32x4*)(sbase + l * 4);
    int   ex0 = (int)(__float_as_uint(ld0[0]) >> 23) - 126;
    float q0n = ldexp_nat(ld0[0], -ex0);         // in [0.5,1) for normal p00
    float q0 = z ? q0n : 0.f;
    float q1 = 0.f, q2 = 0.f, q3 = 0.f;
    int   M  = z ? ex0 : M_DEAD;

    if (tmax <= 0) {
        if (l == (jt >> 2)) {
            float vv = (jt == 0) ? log2_nat(ld0[0]) : NEGV;
            alpha[b] = vv * out_scale;
        }
        return;
    }

    // keep ld0's compiler vmcnt(0) above all DMA issues
    __builtin_amdgcn_sched_barrier(0);

    // issue DMA for row r -> ring[r & 31]; lane l supplies 16B at col l*4
#define ISSUE(R)                                                              \
    __builtin_amdgcn_global_load_lds(                                         \
        (const __attribute__((address_space(1))) void*)(sbase + (size_t)(R) * TXT + l * 4), \
        (__attribute__((address_space(3))) void*)&ring[(R) & 31][0],          \
        16, 0, 0)

    // prologue: rows 1..16 in flight (depth D=16)
#pragma unroll
    for (int r = 1; r <= 16; ++r) ISSUE(r);

    // rows 1..4 ready -> load cur
    asm volatile("s_waitcnt vmcnt(12)" ::: "memory");
    __builtin_amdgcn_sched_barrier(0);
    f32x4 cur0 = *(const f32x4*)&ring[1][l * 4];
    f32x4 cur1 = *(const f32x4*)&ring[2][l * 4];
    f32x4 cur2 = *(const f32x4*)&ring[3][l * 4];
    f32x4 cur3 = *(const f32x4*)&ring[4][l * 4];

    // one DP step on p-row P (all scale ops exact)
#define DP_CORE(P)                                             \
    {                                                          \
        float qb = wave_ror1_f(q3);                            \
        int   Mb = wave_ror1_i(M);                             \
        qb = z ? 0.f : qb;                                     \
        int Mc  = (M > Mb) ? M : Mb;                           \
        int dql = M - Mc;                                      \
        int dqb = Mb - Mc;                                     \
        float qbs = ldexp_nat(qb, dqb);                        \
        float a0 = ldexp_nat(q0, dql);                         \
        float a1 = ldexp_nat(q1, dql);                         \
        float a2 = ldexp_nat(q2, dql);                         \
        float a3 = ldexp_nat(q3, dql);                         \
        q0 = (a0 + qbs) * (P)[0];                              \
        q1 = (a1 + a0)  * (P)[1];                              \
        q2 = (a2 + a1)  * (P)[2];                              \
        q3 = (a3 + a2)  * (P)[3];                              \
        M = Mc;                                                \
    }

    // lane-local renorm: max q -> [0.5,1), M absorbs; all-zero -> M_DEAD
#define RENORM()                                               \
    {                                                          \
        float mloc = fmaxf(fmaxf(q0, q1), fmaxf(q2, q3));      \
        int ex = (int)(__float_as_uint(mloc) >> 23) - 126;     \
        int nex = -ex;                                         \
        q0 = ldexp_nat(q0, nex);                               \
        q1 = ldexp_nat(q1, nex);                               \
        q2 = ldexp_nat(q2, nex);                               \
        q3 = ldexp_nat(q3, nex);                               \
        M = (mloc > 0.f) ? (M + ex) : M_DEAD;                  \
    }

    // main loop: compute rows t..t+3, read rows t+4..t+7, issue rows t+16..t+19
    // invariant at entry: DMAs issued through row t+15, retired through t+3.
    int t = 1;
    for (; t + 7 <= tmax; t += 4) {
        ISSUE(t + 16); ISSUE(t + 17); ISSUE(t + 18); ISSUE(t + 19);
        // issued through t+19; vmcnt(12) -> retired through (t+19)-12 = t+7
        asm volatile("s_waitcnt vmcnt(12)" ::: "memory");
        __builtin_amdgcn_sched_barrier(0);
        f32x4 n0v = *(const f32x4*)&ring[(t + 4) & 31][l * 4];
        f32x4 n1v = *(const f32x4*)&ring[(t + 5) & 31][l * 4];
        f32x4 n2v = *(const f32x4*)&ring[(t + 6) & 31][l * 4];
        f32x4 n3v = *(const f32x4*)&ring[(t + 7) & 31][l * 4];
        DP_CORE(cur0); DP_CORE(cur1); DP_CORE(cur2); DP_CORE(cur3);
        RENORM();
        cur0 = n0v; cur1 = n1v; cur2 = n2v; cur3 = n3v;
    }

    // tail: 4..7 rows remain (t..tmax); cur holds rows t..t+3 (all valid,
    // t <= tmax-3). Rows t+4..tmax are in the ring (issued through t+15).
    asm volatile("s_waitcnt vmcnt(0)" ::: "memory");
    __builtin_amdgcn_sched_barrier(0);

    DP_CORE(cur0);
    if (t + 1 <= tmax) DP_CORE(cur1);
    if (t + 2 <= tmax) DP_CORE(cur2);
    if (t + 3 <= tmax) DP_CORE(cur3);
    RENORM();                           // guard against deep-decay underflow
#pragma unroll
    for (int k = 4; k <= 6; ++k) {
        if (t + k <= tmax) {
            f32x4 rr = *(const f32x4*)&ring[(t + k) & 31][l * 4];
            DP_CORE(rr);
        }
    }

#undef RENORM
#undef DP_CORE
#undef ISSUE

    const int lf = jt >> 2;
    const int ef = jt & 3;
    float v = (ef == 0) ? q0 : (ef == 1) ? q1 : (ef == 2) ? q2 : q3;
    if (l == lf) alpha[b] = (log2_nat(v) + (float)M) * out_scale;
}

// ---------------------------------------------------------------------------
// DP fallback (un-transposed, ln-domain reads from out1) — safety net.
// ---------------------------------------------------------------------------
__global__ __launch_bounds__(256) void dp_kernel_fallback(
    const float* __restrict__ lp,
    const int* __restrict__ tlen, const int* __restrict__ mlen,
    float* __restrict__ alpha)
{
    const int b    = blockIdx.x;
    const int j    = threadIdx.x;
    const int lane = j & 63;
    const int w    = j >> 6;

    const int tl   = tlen[b];
    const int ml   = mlen[b];
    const int tmax = ml - 1;
    const int jt   = tl - 1;
    const float inv_ml = 1.0f / (float)ml;

    __shared__ float bnd[2][4];
    if (threadIdx.x < 8) bnd[threadIdx.x >> 2][threadIdx.x & 3] = NEGV;
    __syncthreads();

    float cur = (j == 0) ? lp[(size_t)(b * TXT) * MEL] : NEGV;
    if (tmax == 0) {
        if (j == jt) alpha[b] = cur * inv_ml;
        return;
    }
    int p = 0;
    for (int t = 1; t <= tmax; ++t) {
        float lpc = lp[((size_t)(b * TXT + j)) * MEL + t];
        float sh = __shfl_up(cur, 1);
        if (lane == 0) sh = (w > 0) ? bnd[p][w - 1] : NEGV;
        float mx = fmaxf(cur, sh);
        float dd = fminf(cur, sh) - mx;
        float nv = mx + __logf(1.0f + __expf(dd)) + lpc;
        if (lane == 63) bnd[p ^ 1][w] = nv;
        if (t == tmax && j == jt) alpha[b] = nv * inv_ml;
        cur = nv;
        __syncthreads();
        p ^= 1;
    }
}

// ---------------------------------------------------------------------------
// Reduce: loss = -mean_b(alpha[b])
// ---------------------------------------------------------------------------
__global__ void reduce_kernel(const float* __restrict__ alpha, float* __restrict__ out)
{
    const int tid = threadIdx.x;
    float v = (tid < B_) ? alpha[tid] : 0.f;
#pragma unroll
    for (int m = 16; m >= 1; m >>= 1) v += __shfl_xor(v, m);
    if (tid == 0) out[0] = -v / (float)B_;
}

// ---------------------------------------------------------------------------
extern "C" void kernel_launch(void* const* d_in, const int* in_sizes, int n_in,
                              void* d_out, int out_size, void* d_ws, size_t ws_size,
                              hipStream_t stream)
{
    const float* mu_logvar = (const float*)d_in[0];
    const float* melspec   = (const float*)d_in[1];
    const int*   tlen      = (const int*)d_in[2];
    const int*   mlen      = (const int*)d_in[3];
    float* out = (float*)d_out;
    float* ws  = (float*)d_ws;

    // ws layout (floats)
    const size_t IV_OFF    = 0;                        // 32*80*256 = 655360
    const size_t M2_OFF    = 655360;                   // 655360
    const size_t S_OFF     = 1310720;                  // 8192
    const size_t ALPHA_OFF = 1318912;                  // 32
    const size_t LPT_OFF   = 1318944;                  // 16,777,216 + pad
    const size_t LPT_ELEMS = (size_t)B_ * MEL * TXT;
    const size_t LPT_PAD   = (size_t)16 * TXT;         // 16 rows prefetch slack
                                                       // (max issued row = tmax+12 <= 2059 < 2064)

    float* IV    = ws + IV_OFF;
    float* M2    = ws + M2_OFF;
    float* S     = ws + S_OFF;
    float* alpha = ws + ALPHA_OFF;
    float* lpT   = ws + LPT_OFF;

    const bool use_lpT = ws_size >= (LPT_OFF + LPT_ELEMS + LPT_PAD) * sizeof(float);

    precompute_kernel<<<dim3(B_), dim3(256), 0, stream>>>(mu_logvar, IV, M2, S);

    logprob_kernel<<<dim3(MEL / 128, TXT / 64, B_), dim3(256), 0, stream>>>(
        melspec, IV, M2, S, out + 1, lpT, use_lpT ? 1 : 0);

    if (use_lpT) {
        dp_kernel<<<dim3(B_), dim3(64), 0, stream>>>(lpT, tlen, mlen, alpha);
    } else {
        dp_kernel_fallback<<<dim3(B_), dim3(256), 0, stream>>>(out + 1, tlen, mlen, alpha);
    }

    reduce_kernel<<<dim3(1), dim3(64), 0, stream>>>(alpha, out);
}

// Round 7
// 311.702 us; speedup vs baseline: 1.6833x; 1.0112x over previous
//
#include <hip/hip_runtime.h>
#include <cstddef>
#include <cstdint>

#define NEGV -1e30f

constexpr int B_    = 32;
constexpr int TXT   = 256;
constexpr int MEL   = 2048;
constexpr int NMEL  = 80;

// 4-step composition groups: group g covers DP steps t = 4g+1 .. 4g+4
constexpr int NGROUPS = 511;    // covers t = 1..2044 (tail steps handled raw)
constexpr int GSTRIDE = 520;    // allocated groups per batch (+ prefetch pad)

#define INV_LN2 1.4426950408889634f
#define LN2     0.6931471805599453f
#define M_DEAD  (-(1 << 30))          // "lane has zero mass" scale marker

typedef float f32x4 __attribute__((ext_vector_type(4)));

__device__ __forceinline__ float wave_ror1_f(float x) {
    int xi = __float_as_int(x);
    int r  = __builtin_amdgcn_update_dpp(xi, xi, 0x13C /*wave_ror:1*/, 0xF, 0xF, false);
    return __int_as_float(r);
}
__device__ __forceinline__ int wave_ror1_i(int x) {
    return __builtin_amdgcn_update_dpp(x, x, 0x13C, 0xF, 0xF, false);
}
__device__ __forceinline__ float exp2_nat(float x) {
#if __has_builtin(__builtin_amdgcn_exp2f)
    return __builtin_amdgcn_exp2f(x);
#else
    float r; asm("v_exp_f32 %0, %1" : "=v"(r) : "v"(x)); return r;
#endif
}
__device__ __forceinline__ float log2_nat(float x) {
#if __has_builtin(__builtin_amdgcn_logf)
    return __builtin_amdgcn_logf(x);
#else
    float r; asm("v_log_f32 %0, %1" : "=v"(r) : "v"(x)); return r;
#endif
}
__device__ __forceinline__ float ldexp_nat(float x, int n) {
#if __has_builtin(__builtin_amdgcn_ldexpf)
    return __builtin_amdgcn_ldexpf(x, n);
#else
    float r; asm("v_ldexp_f32 %0, %1, %2" : "=v"(r) : "v"(x), "v"(n)); return r;
#endif
}

// ---------------------------------------------------------------------------
// Kernel P: per (b,j): iv[c]=exp(-logvar), m2[c]=2*mu*iv, s = sum(mu^2*iv + logvar)
// ---------------------------------------------------------------------------
__global__ __launch_bounds__(256) void precompute_kernel(
    const float* __restrict__ mu_logvar,
    float* __restrict__ IV, float* __restrict__ M2, float* __restrict__ S)
{
    const int b = blockIdx.x;
    const int j = threadIdx.x;
    const float* row = mu_logvar + (size_t)(b * TXT + j) * (2 * NMEL);
    float s = 0.f;
    for (int c = 0; c < NMEL; ++c) {
        float mu = row[c];
        float lv = row[NMEL + c];
        float iv = expf(-lv);
        IV[(b * NMEL + c) * TXT + j] = iv;
        M2[(b * NMEL + c) * TXT + j] = 2.0f * mu * iv;
        s += mu * mu * iv + lv;
    }
    S[b * TXT + j] = s;
}

// ---------------------------------------------------------------------------
// Kernel 1: log_prob (unchanged from R6). out1 = exact ln values;
// lpT[b][t][j] = p = exp(lp) (linear probability factors).
// ---------------------------------------------------------------------------
__global__ __launch_bounds__(256) void logprob_kernel(
    const float* __restrict__ mel,
    const float* __restrict__ IV, const float* __restrict__ M2,
    const float* __restrict__ S,
    float* __restrict__ out1,
    float* __restrict__ lpT,
    int write_lpT)
{
    const int tt0 = blockIdx.x * 128;
    const int j0  = blockIdx.y * 64;
    const int b   = blockIdx.z;
    const int tx  = threadIdx.x & 15;
    const int ty  = threadIdx.x >> 4;

    __shared__ union SM {
        struct { float IV[NMEL][64]; float M2[NMEL][64]; } stage;
        float V[64][132];
    } sm;

    for (int idx = threadIdx.x; idx < NMEL * 64; idx += 256) {
        int c  = idx >> 6;
        int jj = idx & 63;
        sm.stage.IV[c][jj] = IV[(b * NMEL + c) * TXT + j0 + jj];
        sm.stage.M2[c][jj] = M2[(b * NMEL + c) * TXT + j0 + jj];
    }
    __syncthreads();

    float acc[4][8];
#pragma unroll
    for (int a = 0; a < 4; ++a)
#pragma unroll
        for (int d = 0; d < 8; ++d) acc[a][d] = 0.f;

    const float* melb = mel + (size_t)b * NMEL * MEL + tt0 + tx;

#pragma unroll 2
    for (int c = 0; c < NMEL; ++c) {
        float x[8];
#pragma unroll
        for (int d = 0; d < 8; ++d) x[d] = melb[(size_t)c * MEL + 16 * d];
        float4 iv = *(const float4*)&sm.stage.IV[c][ty * 4];
        float4 m2 = *(const float4*)&sm.stage.M2[c][ty * 4];
        float ivr[4] = {iv.x, iv.y, iv.z, iv.w};
        float m2r[4] = {m2.x, m2.y, m2.z, m2.w};
#pragma unroll
        for (int a = 0; a < 4; ++a) {
#pragma unroll
            for (int d = 0; d < 8; ++d) {
                float tmp = fmaf(ivr[a], x[d], -m2r[a]);
                acc[a][d] = fmaf(tmp, x[d], acc[a][d]);
            }
        }
    }

    const float c0 = -0.5f / (float)NMEL;
    float4 sj = *(const float4*)&S[b * TXT + j0 + ty * 4];
    float sjr[4] = {sj.x, sj.y, sj.z, sj.w};

    __syncthreads();
#pragma unroll
    for (int a = 0; a < 4; ++a) {
        const int jl = ty * 4 + a;
#pragma unroll
        for (int d = 0; d < 8; ++d) {
            sm.V[jl][tx + 16 * d] = c0 * (acc[a][d] + sjr[a]);
        }
    }
    __syncthreads();

    const int tid = threadIdx.x;

    {
        const int t4 = (tid & 31) * 4;
        const int jb = tid >> 5;
#pragma unroll
        for (int k = 0; k < 8; ++k) {
            const int jl = jb + 8 * k;
            float4 v = *(const float4*)&sm.V[jl][t4];
            *(float4*)&out1[(size_t)(b * TXT + j0 + jl) * MEL + tt0 + t4] = v;
        }
    }

    if (write_lpT) {
        const int j4 = (tid & 15) * 4;
        const int tb = tid >> 4;
#pragma unroll
        for (int k = 0; k < 8; ++k) {
            const int tl = tb + 16 * k;
            float4 v;
            v.x = exp2_nat(sm.V[j4 + 0][tl] * INV_LN2);
            v.y = exp2_nat(sm.V[j4 + 1][tl] * INV_LN2);
            v.z = exp2_nat(sm.V[j4 + 2][tl] * INV_LN2);
            v.w = exp2_nat(sm.V[j4 + 3][tl] * INV_LN2);
            *(float4*)&lpT[((size_t)b * MEL + tt0 + tl) * TXT + j0 + j4] = v;
        }
    }
}

// ---------------------------------------------------------------------------
// Coeff kernel (NEW, R7): 4-step composed transition coefficients.
// Group g (steps t=4g+1..4g+4):  y[j] = sum_{d=0..4} C_d[j] * x[j-d]
// with C_d built from p rows via the band DP (verified: p==1 -> 1,4,6,4,1).
// Layout coef[b][g][d][j]. Pure parallel work; 148MB traffic ~30-40us.
// j<3 clamp reads j'<0 to 0 — those coeffs only ever multiply lane-0 b-values
// that dp forces to 0, so garbage is harmless (and finite).
// ---------------------------------------------------------------------------
__global__ __launch_bounds__(256) void coeff_kernel(
    const float* __restrict__ lpT, float* __restrict__ coef)
{
    const int c = blockIdx.x;          // chunk: groups 8c..8c+7
    const int b = blockIdx.y;
    const int j = threadIdx.x;

    __shared__ float sp[32][256];      // p rows 32c+1 .. 32c+32
    const int r0 = 32 * c + 1;
    const float* src = lpT + (size_t)b * MEL * TXT;
    for (int idx = threadIdx.x; idx < 32 * 256; idx += 256) {
        int row = idx >> 8;
        int col = idx & 255;
        sp[row][col] = src[(size_t)(r0 + row) * TXT + col];  // row<=2048 < pad
    }
    __syncthreads();

    const int jm1 = (j >= 1) ? j - 1 : 0;
    const int jm2 = (j >= 2) ? j - 2 : 0;
    const int jm3 = (j >= 3) ? j - 3 : 0;

#pragma unroll 2
    for (int gi = 0; gi < 8; ++gi) {
        int g = 8 * c + gi;
        if (g >= NGROUPS) break;
        const float* P1 = sp[4 * gi + 0];
        const float* P2 = sp[4 * gi + 1];
        const float* P3 = sp[4 * gi + 2];
        const float* P4 = sp[4 * gi + 3];
        float p1_0 = P1[j], p1_1 = P1[jm1], p1_2 = P1[jm2], p1_3 = P1[jm3];
        float p2_0 = P2[j], p2_1 = P2[jm1], p2_2 = P2[jm2];
        float p3_0 = P3[j], p3_1 = P3[jm1];
        float p4_0 = P4[j];
        // 2-step bands at positions j, j-1, j-2
        float A0 = p2_0 * p1_0, A1 = p2_0 * (p1_0 + p1_1), A2 = p2_0 * p1_1;
        float B0 = p2_1 * p1_1, B1 = p2_1 * (p1_1 + p1_2), B2 = p2_1 * p1_2;
        float D0 = p2_2 * p1_2, D1 = p2_2 * (p1_2 + p1_3), D2 = p2_2 * p1_3;
        // 3-step bands at positions j, j-1
        float E0 = p3_0 * A0, E1 = p3_0 * (A1 + B0), E2 = p3_0 * (A2 + B1), E3 = p3_0 * B2;
        float F0 = p3_1 * B0, F1 = p3_1 * (B1 + D0), F2 = p3_1 * (B2 + D1), F3 = p3_1 * D2;
        // 4-step band at j
        float* dst = coef + (((size_t)b * GSTRIDE + g) * 5) * 256 + j;
        dst[0]    = p4_0 * E0;
        dst[256]  = p4_0 * (E1 + F0);
        dst[512]  = p4_0 * (E2 + F1);
        dst[768]  = p4_0 * (E3 + F2);
        dst[1024] = p4_0 * F3;
    }
}

// ---------------------------------------------------------------------------
// DP kernel v8 (superstep): 4 DP steps per iteration via precomputed C_d.
// Per superstep: 1 boundary exchange (neighbor's whole f32x4 + M), 1 scale
// reconcile, 20 FMA, 1 renorm — amortizes the per-step overhead that R6
// counters showed dominating (156 cy/step; scale/DPP machinery ~ half).
// Ring: 8 supersteps x 5 rows x 1KB LDS (40KB), DMA depth 7 supersteps,
// counted vmcnt(35). Scale: keep own M; if neighbor bigger (dq>0) downshift
// own and bump M (=> common scale max(M,Mb)); incoming downshifted when
// smaller. Dead lane (M_DEAD): M + max(dq,0) = bM exactly -> adopts scale.
// ---------------------------------------------------------------------------
__global__ __launch_bounds__(64, 1) void dp_super_kernel(
    const float* __restrict__ lpT,
    const float* __restrict__ coef,
    const int* __restrict__ tlen, const int* __restrict__ mlen,
    float* __restrict__ alpha)
{
    const int b = blockIdx.x;
    const int l = threadIdx.x;          // 0..63

    const int tl   = tlen[b];
    const int ml   = mlen[b];
    const int tmax = ml - 1;
    const int jt   = tl - 1;
    const float out_scale = LN2 / (float)ml;

    const float* sbase = lpT  + (size_t)b * MEL * TXT;
    const float* cbase = coef + (size_t)b * GSTRIDE * 5 * 256;
    const bool z = (l == 0);

    __shared__ float ring[40][256];     // 8 supersteps x 5 coeff rows

    // t = 0 init
    f32x4 ld0 = *(const f32x4*)(sbase + l * 4);
    int   ex0 = (int)(__float_as_uint(ld0[0]) >> 23) - 126;
    float q0n = ldexp_nat(ld0[0], -ex0);
    float q0 = z ? q0n : 0.f;
    float q1 = 0.f, q2 = 0.f, q3 = 0.f;
    int   M  = z ? ex0 : M_DEAD;

    if (tmax <= 0) {
        if (l == (jt >> 2)) {
            float vv = (jt == 0) ? log2_nat(ld0[0]) : NEGV;
            alpha[b] = vv * out_scale;
        }
        return;
    }

    __builtin_amdgcn_sched_barrier(0);

    const int nss  = tmax >> 2;         // full supersteps (>=255 here)
    const int tail = tmax & 3;          // 0..3 raw steps after

#define ISSUE1(SRC, SLOT)                                                     \
    __builtin_amdgcn_global_load_lds(                                         \
        (const __attribute__((address_space(1))) void*)(SRC),                 \
        (__attribute__((address_space(3))) void*)&ring[(SLOT)][0], 16, 0, 0)
#define ISSUE5(S)                                                             \
    {                                                                         \
        const float* s_ = cbase + (size_t)(S) * (5 * 256) + l * 4;            \
        const int sl_ = ((S) & 7) * 5;                                        \
        ISSUE1(s_,        sl_ + 0); ISSUE1(s_ + 256,  sl_ + 1);               \
        ISSUE1(s_ + 512,  sl_ + 2); ISSUE1(s_ + 768,  sl_ + 3);               \
        ISSUE1(s_ + 1024, sl_ + 4);                                           \
    }

    // prologue: supersteps 0..6 in flight (35 loads)
#pragma unroll
    for (int s = 0; s < 7; ++s) ISSUE5(s);

    for (int s = 0; s < nss; ++s) {
        ISSUE5(s + 7);                  // <= 517 < GSTRIDE (pad region ok)
        // 40 outstanding; wait for oldest 5 (superstep s) to land
        asm volatile("s_waitcnt vmcnt(35)" ::: "memory");
        __builtin_amdgcn_sched_barrier(0);
        const int sl = (s & 7) * 5;
        f32x4 C0 = *(const f32x4*)&ring[sl + 0][l * 4];
        f32x4 C1 = *(const f32x4*)&ring[sl + 1][l * 4];
        f32x4 C2 = *(const f32x4*)&ring[sl + 2][l * 4];
        f32x4 C3 = *(const f32x4*)&ring[sl + 3][l * 4];
        f32x4 C4 = *(const f32x4*)&ring[sl + 4][l * 4];

        // boundary exchange: neighbor's q0..q3 (= x[4l-4..4l-1]) and M
        float bq0 = wave_ror1_f(q0), bq1 = wave_ror1_f(q1);
        float bq2 = wave_ror1_f(q2), bq3 = wave_ror1_f(q3);
        int   bM  = wave_ror1_i(M);

        int dq   = z ? (-(1 << 28)) : (bM - M);
        int sin_ = (dq < 0) ? dq  : 0;      // downshift incoming if smaller
        int sown = (dq > 0) ? -dq : 0;      // downshift own if neighbor bigger
        int mup  = (dq > 0) ? dq  : 0;

        float a0 = ldexp_nat(q0, sown), a1 = ldexp_nat(q1, sown);
        float a2 = ldexp_nat(q2, sown), a3 = ldexp_nat(q3, sown);
        float b0 = ldexp_nat(bq0, sin_), b1 = ldexp_nat(bq1, sin_);
        float b2 = ldexp_nat(bq2, sin_), b3 = ldexp_nat(bq3, sin_);

        // y[i] = sum_d C_d[i] * x[4l+i-d]; b3-dependent term last (DPP chain)
        float y0 = fmaf(C1[0], b3, fmaf(C2[0], b2, fmaf(C3[0], b1, fmaf(C4[0], b0, C0[0] * a0))));
        float y1 = fmaf(C2[1], b3, fmaf(C3[1], b2, fmaf(C4[1], b1, fmaf(C1[1], a0, C0[1] * a1))));
        float y2 = fmaf(C3[2], b3, fmaf(C4[2], b2, fmaf(C1[2], a1, fmaf(C2[2], a0, C0[2] * a2))));
        float y3 = fmaf(C4[3], b3, fmaf(C1[3], a2, fmaf(C2[3], a1, fmaf(C3[3], a0, C0[3] * a3))));

        // renorm (once per 4 steps)
        float mloc = fmaxf(fmaxf(y0, y1), fmaxf(y2, y3));
        int ex  = (int)(__float_as_uint(mloc) >> 23) - 126;
        int nex = -ex;
        q0 = ldexp_nat(y0, nex); q1 = ldexp_nat(y1, nex);
        q2 = ldexp_nat(y2, nex); q3 = ldexp_nat(y3, nex);
        int Mn = M + mup + ex;
        M = (mloc > 0.f) ? Mn : M_DEAD;
    }

    // drain remaining ring DMAs before tail / exit
    asm volatile("s_waitcnt vmcnt(0)" ::: "memory");
    __builtin_amdgcn_sched_barrier(0);

    // tail: 0..3 raw single steps on p rows (lpT padded -> loads safe)
    {
        const int t0 = 4 * nss + 1;
        f32x4 pr0 = *(const f32x4*)(sbase + (size_t)(t0 + 0) * TXT + l * 4);
        f32x4 pr1 = *(const f32x4*)(sbase + (size_t)(t0 + 1) * TXT + l * 4);
        f32x4 pr2 = *(const f32x4*)(sbase + (size_t)(t0 + 2) * TXT + l * 4);

#define STEP1(P)                                                   \
    {                                                              \
        float qb = wave_ror1_f(q3);                                \
        int   Mb = wave_ror1_i(M);                                 \
        int dq   = z ? (-(1 << 28)) : (Mb - M);                    \
        int si   = (dq < 0) ? dq  : 0;                             \
        int so   = (dq > 0) ? -dq : 0;                             \
        int mu   = (dq > 0) ? dq  : 0;                             \
        float a0 = ldexp_nat(q0, so), a1 = ldexp_nat(q1, so);      \
        float a2 = ldexp_nat(q2, so), a3 = ldexp_nat(q3, so);      \
        float bb = ldexp_nat(qb, si);                              \
        q0 = (a0 + bb) * (P)[0];                                   \
        q1 = (a1 + a0) * (P)[1];                                   \
        q2 = (a2 + a1) * (P)[2];                                   \
        q3 = (a3 + a2) * (P)[3];                                   \
        M += mu;                                                   \
    }
        if (tail >= 1) STEP1(pr0);
        if (tail >= 2) STEP1(pr1);
        if (tail >= 3) STEP1(pr2);
#undef STEP1
    }
#undef ISSUE5
#undef ISSUE1

    const int lf = jt >> 2;
    const int ef = jt & 3;
    float v = (ef == 0) ? q0 : (ef == 1) ? q1 : (ef == 2) ? q2 : q3;
    if (l == lf) alpha[b] = (log2_nat(v) + (float)M) * out_scale;
}

// ---------------------------------------------------------------------------
// DP kernel v7 (kept as mid-tier fallback if ws can't fit the coeff array).
// ---------------------------------------------------------------------------
__global__ __launch_bounds__(64, 1) void dp_lin_kernel(
    const float* __restrict__ lpT,
    const int* __restrict__ tlen, const int* __restrict__ mlen,
    float* __restrict__ alpha)
{
    const int b = blockIdx.x;
    const int l = threadIdx.x;

    const int tl   = tlen[b];
    const int ml   = mlen[b];
    const int tmax = ml - 1;
    const int jt   = tl - 1;
    const float out_scale = LN2 / (float)ml;

    const float* sbase = lpT + (size_t)b * MEL * TXT;
    const bool z = (l == 0);

    __shared__ float ring[32][256];

    f32x4 ld0 = *(const f32x4*)(sbase + l * 4);
    int   ex0 = (int)(__float_as_uint(ld0[0]) >> 23) - 126;
    float q0n = ldexp_nat(ld0[0], -ex0);
    float q0 = z ? q0n : 0.f;
    float q1 = 0.f, q2 = 0.f, q3 = 0.f;
    int   M  = z ? ex0 : M_DEAD;

    if (tmax <= 0) {
        if (l == (jt >> 2)) {
            float vv = (jt == 0) ? log2_nat(ld0[0]) : NEGV;
            alpha[b] = vv * out_scale;
        }
        return;
    }

    __builtin_amdgcn_sched_barrier(0);

#define ISSUE(R)                                                              \
    __builtin_amdgcn_global_load_lds(                                         \
        (const __attribute__((address_space(1))) void*)(sbase + (size_t)(R) * TXT + l * 4), \
        (__attribute__((address_space(3))) void*)&ring[(R) & 31][0],          \
        16, 0, 0)

#pragma unroll
    for (int r = 1; r <= 16; ++r) ISSUE(r);

    asm volatile("s_waitcnt vmcnt(12)" ::: "memory");
    __builtin_amdgcn_sched_barrier(0);
    f32x4 cur0 = *(const f32x4*)&ring[1][l * 4];
    f32x4 cur1 = *(const f32x4*)&ring[2][l * 4];
    f32x4 cur2 = *(const f32x4*)&ring[3][l * 4];
    f32x4 cur3 = *(const f32x4*)&ring[4][l * 4];

#define DP_CORE(P)                                             \
    {                                                          \
        float qb = wave_ror1_f(q3);                            \
        int   Mb = wave_ror1_i(M);                             \
        qb = z ? 0.f : qb;                                     \
        int Mc  = (M > Mb) ? M : Mb;                           \
        int dql = M - Mc;                                      \
        int dqb = Mb - Mc;                                     \
        float qbs = ldexp_nat(qb, dqb);                        \
        float a0 = ldexp_nat(q0, dql);                         \
        float a1 = ldexp_nat(q1, dql);                         \
        float a2 = ldexp_nat(q2, dql);                         \
        float a3 = ldexp_nat(q3, dql);                         \
        q0 = (a0 + qbs) * (P)[0];                              \
        q1 = (a1 + a0)  * (P)[1];                              \
        q2 = (a2 + a1)  * (P)[2];                              \
        q3 = (a3 + a2)  * (P)[3];                              \
        M = Mc;                                                \
    }
#define RENORM()                                               \
    {                                                          \
        float mloc = fmaxf(fmaxf(q0, q1), fmaxf(q2, q3));      \
        int ex = (int)(__float_as_uint(mloc) >> 23) - 126;     \
        int nex = -ex;                                         \
        q0 = ldexp_nat(q0, nex);                               \
        q1 = ldexp_nat(q1, nex);                               \
        q2 = ldexp_nat(q2, nex);                               \
        q3 = ldexp_nat(q3, nex);                               \
        M = (mloc > 0.f) ? (M + ex) : M_DEAD;                  \
    }

    int t = 1;
    for (; t + 7 <= tmax; t += 4) {
        ISSUE(t + 16); ISSUE(t + 17); ISSUE(t + 18); ISSUE(t + 19);
        asm volatile("s_waitcnt vmcnt(12)" ::: "memory");
        __builtin_amdgcn_sched_barrier(0);
        f32x4 n0v = *(const f32x4*)&ring[(t + 4) & 31][l * 4];
        f32x4 n1v = *(const f32x4*)&ring[(t + 5) & 31][l * 4];
        f32x4 n2v = *(const f32x4*)&ring[(t + 6) & 31][l * 4];
        f32x4 n3v = *(const f32x4*)&ring[(t + 7) & 31][l * 4];
        DP_CORE(cur0); DP_CORE(cur1); DP_CORE(cur2); DP_CORE(cur3);
        RENORM();
        cur0 = n0v; cur1 = n1v; cur2 = n2v; cur3 = n3v;
    }

    asm volatile("s_waitcnt vmcnt(0)" ::: "memory");
    __builtin_amdgcn_sched_barrier(0);

    DP_CORE(cur0);
    if (t + 1 <= tmax) DP_CORE(cur1);
    if (t + 2 <= tmax) DP_CORE(cur2);
    if (t + 3 <= tmax) DP_CORE(cur3);
    RENORM();
#pragma unroll
    for (int k = 4; k <= 6; ++k) {
        if (t + k <= tmax) {
            f32x4 rr = *(const f32x4*)&ring[(t + k) & 31][l * 4];
            DP_CORE(rr);
        }
    }
#undef RENORM
#undef DP_CORE
#undef ISSUE

    const int lf = jt >> 2;
    const int ef = jt & 3;
    float v = (ef == 0) ? q0 : (ef == 1) ? q1 : (ef == 2) ? q2 : q3;
    if (l == lf) alpha[b] = (log2_nat(v) + (float)M) * out_scale;
}

// ---------------------------------------------------------------------------
// DP fallback (un-transposed, ln-domain reads from out1) — safety net.
// ---------------------------------------------------------------------------
__global__ __launch_bounds__(256) void dp_kernel_fallback(
    const float* __restrict__ lp,
    const int* __restrict__ tlen, const int* __restrict__ mlen,
    float* __restrict__ alpha)
{
    const int b    = blockIdx.x;
    const int j    = threadIdx.x;
    const int lane = j & 63;
    const int w    = j >> 6;

    const int tl   = tlen[b];
    const int ml   = mlen[b];
    const int tmax = ml - 1;
    const int jt   = tl - 1;
    const float inv_ml = 1.0f / (float)ml;

    __shared__ float bnd[2][4];
    if (threadIdx.x < 8) bnd[threadIdx.x >> 2][threadIdx.x & 3] = NEGV;
    __syncthreads();

    float cur = (j == 0) ? lp[(size_t)(b * TXT) * MEL] : NEGV;
    if (tmax == 0) {
        if (j == jt) alpha[b] = cur * inv_ml;
        return;
    }
    int p = 0;
    for (int t = 1; t <= tmax; ++t) {
        float lpc = lp[((size_t)(b * TXT + j)) * MEL + t];
        float sh = __shfl_up(cur, 1);
        if (lane == 0) sh = (w > 0) ? bnd[p][w - 1] : NEGV;
        float mx = fmaxf(cur, sh);
        float dd = fminf(cur, sh) - mx;
        float nv = mx + __logf(1.0f + __expf(dd)) + lpc;
        if (lane == 63) bnd[p ^ 1][w] = nv;
        if (t == tmax && j == jt) alpha[b] = nv * inv_ml;
        cur = nv;
        __syncthreads();
        p ^= 1;
    }
}

// ---------------------------------------------------------------------------
// Reduce: loss = -mean_b(alpha[b])
// ---------------------------------------------------------------------------
__global__ void reduce_kernel(const float* __restrict__ alpha, float* __restrict__ out)
{
    const int tid = threadIdx.x;
    float v = (tid < B_) ? alpha[tid] : 0.f;
#pragma unroll
    for (int m = 16; m >= 1; m >>= 1) v += __shfl_xor(v, m);
    if (tid == 0) out[0] = -v / (float)B_;
}

// ---------------------------------------------------------------------------
extern "C" void kernel_launch(void* const* d_in, const int* in_sizes, int n_in,
                              void* d_out, int out_size, void* d_ws, size_t ws_size,
                              hipStream_t stream)
{
    const float* mu_logvar = (const float*)d_in[0];
    const float* melspec   = (const float*)d_in[1];
    const int*   tlen      = (const int*)d_in[2];
    const int*   mlen      = (const int*)d_in[3];
    float* out = (float*)d_out;
    float* ws  = (float*)d_ws;

    // ws layout (floats)
    const size_t IV_OFF    = 0;                        // 655360
    const size_t M2_OFF    = 655360;                   // 655360
    const size_t S_OFF     = 1310720;                  // 8192
    const size_t ALPHA_OFF = 1318912;                  // 32
    const size_t LPT_OFF   = 1318944;
    const size_t LPT_ELEMS = (size_t)B_ * MEL * TXT;   // 16,777,216
    const size_t LPT_PAD   = (size_t)16 * TXT;         // prefetch/tail slack
    const size_t COEF_OFF  = LPT_OFF + LPT_ELEMS + LPT_PAD;
    const size_t COEF_ELEMS = (size_t)B_ * GSTRIDE * 5 * 256;  // ~21.3M

    float* IV    = ws + IV_OFF;
    float* M2    = ws + M2_OFF;
    float* S     = ws + S_OFF;
    float* alpha = ws + ALPHA_OFF;
    float* lpT   = ws + LPT_OFF;
    float* coef  = ws + COEF_OFF;

    const bool use_lpT  = ws_size >= (LPT_OFF + LPT_ELEMS + LPT_PAD) * sizeof(float);
    const bool use_coef = ws_size >= (COEF_OFF + COEF_ELEMS) * sizeof(float);

    precompute_kernel<<<dim3(B_), dim3(256), 0, stream>>>(mu_logvar, IV, M2, S);

    logprob_kernel<<<dim3(MEL / 128, TXT / 64, B_), dim3(256), 0, stream>>>(
        melspec, IV, M2, S, out + 1, lpT, use_lpT ? 1 : 0);

    if (use_coef) {
        coeff_kernel<<<dim3(64, B_), dim3(256), 0, stream>>>(lpT, coef);
        dp_super_kernel<<<dim3(B_), dim3(64), 0, stream>>>(lpT, coef, tlen, mlen, alpha);
    } else if (use_lpT) {
        dp_lin_kernel<<<dim3(B_), dim3(64), 0, stream>>>(lpT, tlen, mlen, alpha);
    } else {
        dp_kernel_fallback<<<dim3(B_), dim3(256), 0, stream>>>(out + 1, tlen, mlen, alpha);
    }

    reduce_kernel<<<dim3(1), dim3(64), 0, stream>>>(alpha, out);
}